// Round 4
// baseline (421.870 us; speedup 1.0000x reference)
//
#include <hip/hip_runtime.h>

typedef __bf16  bf16x8 __attribute__((ext_vector_type(8)));
typedef float   f32x4  __attribute__((ext_vector_type(4)));
typedef unsigned short u16;

__device__ __forceinline__ u16 f2bf(float f) {
  union { float f; unsigned u32; } c; c.f = f;
  unsigned r = c.u32 + 0x7fffu + ((c.u32 >> 16) & 1u);   // RNE
  return (u16)(r >> 16);
}
__device__ __forceinline__ float bf2f(u16 u) {
  union { unsigned u32; float f; } c; c.u32 = (unsigned)u << 16; return c.f;
}

// async global->LDS, 16B per lane; HW places lane i at (wave-uniform base)+i*16
__device__ __forceinline__ void async16(const void* g, void* l) {
  __builtin_amdgcn_global_load_lds(
      (const __attribute__((address_space(1))) unsigned*)g,
      (__attribute__((address_space(3))) unsigned*)l, 16, 0, 0);
}

// ---------------- circulant builder: Ct[n*512+k] = w[(n-k)&511] / sqrt(512)
__global__ __launch_bounds__(256) void build_ct(const float* __restrict__ w,
                                                u16* __restrict__ ct) {
  int idx = blockIdx.x * 256 + threadIdx.x;          // 0..262143
  int n = idx >> 9, k = idx & 511;
  float v = w[(n - k) & 511] * 0.04419417382415922f; // 1/sqrt(512)
  ct[idx] = f2bf(v);
}

// ---------------- transpose + cast: out(bf16)[c][r] = in(fp32)[r][c]
__global__ __launch_bounds__(256) void transpose_w(const float* __restrict__ in,
                                                   u16* __restrict__ out,
                                                   int R, int C) {
  __shared__ float tile[32][33];
  int bx = blockIdx.x * 32;
  int by = blockIdx.y * 32;
  int tx = threadIdx.x & 31, ty = threadIdx.x >> 5;
#pragma unroll
  for (int r = ty; r < 32; r += 8)
    tile[r][tx] = in[(size_t)(by + r) * C + bx + tx];
  __syncthreads();
#pragma unroll
  for (int r = ty; r < 32; r += 8)
    out[(size_t)(bx + r) * R + by + tx] = f2bf(tile[tx][r]);
}

// ---------------- LayerNorm [64,512] slab, fp32 in, single global read
__global__ __launch_bounds__(512, 2) void ln_f32(const float* __restrict__ x,
                                                 const float* __restrict__ g,
                                                 const float* __restrict__ beta,
                                                 u16* __restrict__ out) {
  const int tid = threadIdx.x;
  const size_t base = (size_t)blockIdx.x * 32768;
  float4 v[16];
  float s = 0.f, ss = 0.f;
#pragma unroll
  for (int j = 0; j < 16; ++j) {
    v[j] = *(const float4*)(x + base + tid * 4 + j * 2048);
    s  += v[j].x + v[j].y + v[j].z + v[j].w;
    ss += v[j].x * v[j].x + v[j].y * v[j].y + v[j].z * v[j].z + v[j].w * v[j].w;
  }
#pragma unroll
  for (int off = 32; off > 0; off >>= 1) {
    s += __shfl_down(s, off, 64);
    ss += __shfl_down(ss, off, 64);
  }
  __shared__ float red[16];
  int wave = tid >> 6, lane = tid & 63;
  if (lane == 0) { red[wave] = s; red[8 + wave] = ss; }
  __syncthreads();
  float S = 0.f, SS = 0.f;
#pragma unroll
  for (int wv = 0; wv < 8; ++wv) { S += red[wv]; SS += red[8 + wv]; }
  const float inv = 1.0f / 32768.0f;
  float mu = S * inv;
  float rs = rsqrtf(SS * inv - mu * mu + 1e-5f);
#pragma unroll
  for (int j = 0; j < 16; ++j) {
    const int i = tid * 4 + j * 2048;
    float4 gv = *(const float4*)(g + i);
    float4 bv = *(const float4*)(beta + i);
    uint2 o;
    o.x = (unsigned)f2bf((v[j].x - mu) * rs * gv.x + bv.x) |
          ((unsigned)f2bf((v[j].y - mu) * rs * gv.y + bv.y) << 16);
    o.y = (unsigned)f2bf((v[j].z - mu) * rs * gv.z + bv.z) |
          ((unsigned)f2bf((v[j].w - mu) * rs * gv.w + bv.w) << 16);
    *(uint2*)(out + base + i) = o;
  }
}

// ---------------- LayerNorm [64,512] slab, bf16 in, single global read
__global__ __launch_bounds__(512, 2) void ln_bf16(const u16* __restrict__ x,
                                                  const float* __restrict__ g,
                                                  const float* __restrict__ beta,
                                                  u16* __restrict__ out) {
  const int tid = threadIdx.x;
  const size_t base = (size_t)blockIdx.x * 32768;
  uint4 v[8];
  float s = 0.f, ss = 0.f;
#pragma unroll
  for (int j = 0; j < 8; ++j) {
    v[j] = *(const uint4*)(x + base + tid * 8 + j * 4096);
    const unsigned* a = &v[j].x;
#pragma unroll
    for (int t = 0; t < 4; ++t) {
      float lo = bf2f((u16)(a[t] & 0xffff)), hi = bf2f((u16)(a[t] >> 16));
      s += lo + hi; ss += lo * lo + hi * hi;
    }
  }
#pragma unroll
  for (int off = 32; off > 0; off >>= 1) {
    s += __shfl_down(s, off, 64);
    ss += __shfl_down(ss, off, 64);
  }
  __shared__ float red[16];
  int wave = tid >> 6, lane = tid & 63;
  if (lane == 0) { red[wave] = s; red[8 + wave] = ss; }
  __syncthreads();
  float S = 0.f, SS = 0.f;
#pragma unroll
  for (int wv = 0; wv < 8; ++wv) { S += red[wv]; SS += red[8 + wv]; }
  const float inv = 1.0f / 32768.0f;
  float mu = S * inv;
  float rs = rsqrtf(SS * inv - mu * mu + 1e-5f);
#pragma unroll
  for (int j = 0; j < 8; ++j) {
    const int i = tid * 8 + j * 4096;
    const unsigned* a = &v[j].x;
    uint4 o;
    unsigned* ov = &o.x;
#pragma unroll
    for (int t = 0; t < 4; ++t) {
      float lo = bf2f((u16)(a[t] & 0xffff)), hi = bf2f((u16)(a[t] >> 16));
      float glo = g[i + 2 * t], ghi = g[i + 2 * t + 1];
      float blo = beta[i + 2 * t], bhi = beta[i + 2 * t + 1];
      ov[t] = (unsigned)f2bf((lo - mu) * rs * glo + blo) |
              ((unsigned)f2bf((hi - mu) * rs * ghi + bhi) << 16);
    }
    *(uint4*)(out + base + i) = o;
  }
}

// ---------------- GEMM: C[M,N] = A[M,K](bf16) @ Bt[N,K](bf16)^T
// 256x256 tile, BK=64, 512 thr = 8 waves (2M x 4N), per-wave 128x64,
// mfma_f32_16x16x32_bf16, acc[8][4] f32x4.
// LDS 128KB: A,B each 2buf x [256][64] u16, chunk swizzle (slot s of row r
// holds global chunk s^(r&7)) -> 0 bank conflicts (verified).
// Deep-prefetch schedule (fix for round-3's latency stall): ALL 8 loads of
// tile t+1 are issued at tile t phase 0 (race-free: issued after the
// tile-boundary barrier, which follows every wave's lgkmcnt(0)-drained reads
// of buf^1). Waits: vmcnt(8) at end of ph0 (leaves exactly t+1's 8 loads;
// proves t's B1,A1 landed; in-flight >= 4 phases ~ HBM latency), vmcnt(4) at
// end of merged ph2+3 (proves t+1's A0,B0 landed -> loop invariant). Loads
// retire oldest-first, so each wait+barrier collectively covers the unit
// before any wave reads it. 6 barriers/tile; last tile peeled (branch-free
// hot loop). 3 MFMA clusters per tile: 16,16,32.
// MODE 0: plain, bf16 out   MODE 1: +bias, ReLU, bf16 out
// MODE 2: +bias, +resid(fp32), fp32 out
template <int MODE>
__global__ __launch_bounds__(512, 2) void gemm_bt(
    const u16* __restrict__ A, const u16* __restrict__ Bt,
    const float* __restrict__ bias, const float* __restrict__ resid,
    float* __restrict__ Cf, u16* __restrict__ Cb,
    int M, int N, int K, int MT) {
  __shared__ u16 As[32768];   // 2 x [256][64]
  __shared__ u16 Bs[32768];

  const int tid  = threadIdx.x;
  const int lane = tid & 63;
  const int wave = tid >> 6;
  const int l16  = lane & 15, quad = lane >> 4;
  const int wr = wave >> 2, wc = wave & 3;          // 2M x 4N wave grid

  // bijective XCD-aware block swizzle (m204)
  const int nwg = gridDim.x;
  const int q8 = nwg >> 3, r8 = nwg & 7;
  const int xcd = blockIdx.x & 7, loc = blockIdx.x >> 3;
  const int wgid =
      (xcd < r8 ? xcd * (q8 + 1) : r8 * (q8 + 1) + (xcd - r8) * q8) + loc;
  const int bm = wgid % MT, bn = wgid / MT;
  const int m0 = bm * 256, n0 = bn * 256;
  (void)M;

  // ---- staging geometry (lane-linear dests; source pre-swizzled) ----
  const int srow   = tid >> 3;                       // 0..63
  const int grp    = tid >> 8;                       // 0..1
  const int srow32 = srow & 31;                      // 0..31
  const int gch    = ((tid & 7) ^ (srow & 7)) * 8;   // swizzled chunk (u16)
  const u16* agb = A  + (size_t)(m0 + srow) * K + gch;
  const u16* bgb = Bt + (size_t)(n0 + grp * 64 + srow32) * K + gch;
  const int adst = tid * 8;                          // == srow*64 + slot*8
  const int bdst = grp * 4096 + (tid & 255) * 8;     // == row*64 + slot*8

  // A-unit qm: rows qm*64+[0,64) and qm*64+128+[0,64)  -> LDS qm*4096 (+8192)
#define STAGE_A(t1, qm) {                                                   \
    const u16* g_ = agb + (size_t)(qm) * 64 * K + (t1) * 64;                \
    u16* d_ = As + (((t1) & 1) << 14) + (qm) * 4096 + adst;                 \
    async16(g_, d_);                                                        \
    async16(g_ + (size_t)128 * K, d_ + 8192); }
  // B-unit qn: rows grp*64+qn*32+[0,32) and +128      -> LDS qn*2048 (+8192)
#define STAGE_B(t1, qn) {                                                   \
    const u16* g_ = bgb + (size_t)(qn) * 32 * K + (t1) * 64;                \
    u16* d_ = Bs + (((t1) & 1) << 14) + (qn) * 2048 + bdst;                 \
    async16(g_, d_);                                                        \
    async16(g_ + (size_t)128 * K, d_ + 8192); }
  // whole next tile, unit order A0,B0,B1,A1 (first 4 loads = A0,B0)
#define STAGE_ALL(t1) { STAGE_A(t1, 0); STAGE_B(t1, 0);                     \
                        STAGE_B(t1, 1); STAGE_A(t1, 1); }

  // ---- fragment read offsets (u16 units); row = wr*128+qm*64+m*16+l16 etc.
  const int arow = wr * 8192 + l16 * 64;
  const int brow = wc * 4096 + l16 * 64;
  const int sw0 = ((0 + quad) ^ (l16 & 7)) * 8;      // k-chunks 0..3
  const int sw1 = ((4 + quad) ^ (l16 & 7)) * 8;      // k-chunks 4..7

  bf16x8 av[4][2], bv[2][2][2];
  f32x4 acc[8][4];
#pragma unroll
  for (int i = 0; i < 8; ++i)
#pragma unroll
    for (int j = 0; j < 4; ++j) acc[i][j] = (f32x4){0.f, 0.f, 0.f, 0.f};

#define LDA(qm) {                                                           \
    const int ab = (buf << 14) + (qm) * 4096 + arow;                        \
    _Pragma("unroll")                                                       \
    for (int m_ = 0; m_ < 4; ++m_) {                                        \
      av[m_][0] = *(const bf16x8*)&As[ab + m_ * 1024 + sw0];                \
      av[m_][1] = *(const bf16x8*)&As[ab + m_ * 1024 + sw1];                \
    } }
#define LDB(qn) {                                                           \
    const int bb = (buf << 14) + (qn) * 2048 + brow;                        \
    _Pragma("unroll")                                                       \
    for (int n_ = 0; n_ < 2; ++n_) {                                        \
      bv[qn][n_][0] = *(const bf16x8*)&Bs[bb + n_ * 1024 + sw0];            \
      bv[qn][n_][1] = *(const bf16x8*)&Bs[bb + n_ * 1024 + sw1];            \
    } }
#define MFMA_Q(qm, qn)                                                      \
    __builtin_amdgcn_s_setprio(1);                                          \
    _Pragma("unroll")                                                       \
    for (int m_ = 0; m_ < 4; ++m_) {                                        \
      _Pragma("unroll")                                                     \
      for (int n_ = 0; n_ < 2; ++n_) {                                      \
        acc[(qm)*4+m_][(qn)*2+n_] = __builtin_amdgcn_mfma_f32_16x16x32_bf16(\
            av[m_][0], bv[qn][n_][0], acc[(qm)*4+m_][(qn)*2+n_], 0, 0, 0);  \
        acc[(qm)*4+m_][(qn)*2+n_] = __builtin_amdgcn_mfma_f32_16x16x32_bf16(\
            av[m_][1], bv[qn][n_][1], acc[(qm)*4+m_][(qn)*2+n_], 0, 0, 0);  \
      } }                                                                   \
    __builtin_amdgcn_s_setprio(0);

#define SB    __builtin_amdgcn_sched_barrier(0)
#define BAR   __builtin_amdgcn_s_barrier()
#define LGKM0 asm volatile("s_waitcnt lgkmcnt(0)" ::: "memory")
#define VM(n) asm volatile("s_waitcnt vmcnt(" #n ")" ::: "memory")

  const int NT = K >> 6;        // K-tiles of 64 (>= 2 for all our shapes)

  // prologue: stage tile 0; A0,B0 landed; barrier
  STAGE_ALL(0);
  VM(4);
  SB; BAR;

  for (int t = 0; t < NT - 1; ++t) {
    const int buf = t & 1;
    // ---- phase 0 : quadrant (qm0,qn0); burst-stage ALL of tile t+1
    STAGE_ALL(t + 1);
    LDA(0); LDB(0);
    BAR; LGKM0; SB;
    MFMA_Q(0, 0);
    SB;
    VM(8);                            // leaves t+1's 8; t's B1,A1 landed
    SB; BAR;
    // ---- phase 1 : quadrant (qm0,qn1)
    LDB(1);
    BAR; LGKM0; SB;
    MFMA_Q(0, 1);
    SB; BAR;
    // ---- phase 2+3 : quadrants (qm1,qn0),(qm1,qn1)
    LDA(1);
    BAR; LGKM0; SB;
    MFMA_Q(1, 0);
    MFMA_Q(1, 1);
    SB;
    VM(4);                            // t+1's A0,B0 landed (loop invariant)
    SB; BAR;
  }

  {   // ---- final tile (no staging)
    const int buf = (NT - 1) & 1;
    LDA(0); LDB(0);
    BAR; LGKM0; SB;
    MFMA_Q(0, 0);
    SB; VM(2); SB; BAR;               // B1 landed
    LDB(1);
    BAR; LGKM0; SB;
    MFMA_Q(0, 1);
    SB; VM(0); SB; BAR;               // A1 landed
    LDA(1);
    LGKM0; SB;
    MFMA_Q(1, 0);
    MFMA_Q(1, 1);
  }

#undef STAGE_A
#undef STAGE_B
#undef STAGE_ALL
#undef LDA
#undef LDB
#undef MFMA_Q
#undef SB
#undef BAR
#undef LGKM0
#undef VM

  // epilogue: 16x16x32 C/D layout: col = lane&15, row = (lane>>4)*4 + reg
#pragma unroll
  for (int qn = 0; qn < 2; ++qn)
#pragma unroll
    for (int n = 0; n < 2; ++n) {
      const int col = n0 + wc * 64 + qn * 32 + n * 16 + l16;
      float bj = 0.f;
      if (MODE >= 1) bj = bias[col];
#pragma unroll
      for (int qm = 0; qm < 2; ++qm)
#pragma unroll
        for (int m = 0; m < 4; ++m) {
          const int row0 = m0 + wr * 128 + qm * 64 + m * 16 + quad * 4;
          f32x4 a = acc[qm * 4 + m][qn * 2 + n];
#pragma unroll
          for (int r = 0; r < 4; ++r) {
            float v = a[r] + bj;
            if (MODE == 1) v = fmaxf(v, 0.f);
            const size_t idx = (size_t)(row0 + r) * N + col;
            if (MODE == 2) { v += resid[idx]; Cf[idx] = v; }
            else           Cb[idx] = f2bf(v);
          }
        }
    }
}

extern "C" void kernel_launch(void* const* d_in, const int* in_sizes, int n_in,
                              void* d_out, int out_size, void* d_ws,
                              size_t ws_size, hipStream_t stream) {
  const float* x    = (const float*)d_in[0];  // [512,64,512] fp32
  const float* w    = (const float*)d_in[1];  // [1,512]
  const float* ln1w = (const float*)d_in[2];  // [64,512]
  const float* ln1b = (const float*)d_in[3];
  const float* ln2w = (const float*)d_in[4];
  const float* ln2b = (const float*)d_in[5];
  const float* w1   = (const float*)d_in[6];  // [512,2048]
  const float* b1   = (const float*)d_in[7];  // [2048]
  const float* w2   = (const float*)d_in[8];  // [2048,512]
  const float* b2   = (const float*)d_in[9];  // [512]
  float* out = (float*)d_out;                 // [512,64,512] fp32

  char* ws = (char*)d_ws;
  // y overlaps h1+h2 (both dead before FFN1 writes y)
  u16*   y   = (u16*)(ws);                  // [32768,2048] bf16  134,217,728 B @ 0
  u16*   h1  = (u16*)(ws);                  // [32768,512]  bf16   33,554,432 B @ 0
  u16*   h2  = (u16*)(ws + 33554432);       // [32768,512]  bf16   33,554,432 B
  u16*   h3  = (u16*)(ws + 134217728);      // [32768,512]  bf16   33,554,432 B
  u16*   ct  = (u16*)(ws + 167772160);      // [512,512]    bf16      524,288 B
  u16*   w1t = (u16*)(ws + 168296448);      // [2048,512]   bf16    2,097,152 B
  u16*   w2t = (u16*)(ws + 170393600);      // [512,2048]   bf16    2,097,152 B
  // peak ws use: 172,490,752 B

  build_ct<<<1024, 256, 0, stream>>>(w, ct);
  transpose_w<<<dim3(64, 16), 256, 0, stream>>>(w1, w1t, 512, 2048);
  transpose_w<<<dim3(16, 64), 256, 0, stream>>>(w2, w2t, 2048, 512);

  // LN1: x(fp32) -> h1(bf16), single global read
  ln_f32<<<512, 512, 0, stream>>>(x, ln1w, ln1b, h1);
  // freq filter: h2(bf16) = h1 @ C   (M=32768, N=512, K=512) -> 256 blocks
  gemm_bt<0><<<256, 512, 0, stream>>>(h1, ct, nullptr, nullptr,
                                      nullptr, h2, 32768, 512, 512, 128);
  // LN2: h2(bf16) -> h3(bf16)
  ln_bf16<<<512, 512, 0, stream>>>(h2, ln2w, ln2b, h3);
  // FFN1: y(bf16) = relu(h3 @ w1 + b1)  (N=2048) -> 1024 blocks
  gemm_bt<1><<<1024, 512, 0, stream>>>(h3, w1t, b1, nullptr,
                                       nullptr, y, 32768, 2048, 512, 128);
  // FFN2 + residual: out(fp32) = y @ w2 + b2 + x  (K=2048) -> 256 blocks
  gemm_bt<2><<<256, 512, 0, stream>>>(y, w2t, b2, x,
                                      out, nullptr, 32768, 512, 2048, 128);
}

// Round 5
// 331.862 us; speedup vs baseline: 1.2712x; 1.2712x over previous
//
#include <hip/hip_runtime.h>

typedef __bf16  bf16x8 __attribute__((ext_vector_type(8)));
typedef float   f32x4  __attribute__((ext_vector_type(4)));
typedef unsigned short u16;

__device__ __forceinline__ u16 f2bf(float f) {
  union { float f; unsigned u32; } c; c.f = f;
  unsigned r = c.u32 + 0x7fffu + ((c.u32 >> 16) & 1u);   // RNE
  return (u16)(r >> 16);
}
__device__ __forceinline__ float bf2f(u16 u) {
  union { unsigned u32; float f; } c; c.u32 = (unsigned)u << 16; return c.f;
}

// async global->LDS, 16B per lane; HW places lane i at (wave-uniform base)+i*16
__device__ __forceinline__ void async16(const void* g, void* l) {
  __builtin_amdgcn_global_load_lds(
      (const __attribute__((address_space(1))) unsigned*)g,
      (__attribute__((address_space(3))) unsigned*)l, 16, 0, 0);
}

// ---------------- fused setup: build_ct + transpose(w1) + transpose(w2)
// blocks [0,1024): Ct[n*512+k] = w[(n-k)&511] / sqrt(512)
// blocks [1024,2048): w1t(bf16)[c][r] = w1(fp32)[r][c], R=512,C=2048
// blocks [2048,3072): w2t(bf16)[c][r] = w2(fp32)[r][c], R=2048,C=512
__global__ __launch_bounds__(256) void setup_all(
    const float* __restrict__ w,  u16* __restrict__ ct,
    const float* __restrict__ w1, u16* __restrict__ w1t,
    const float* __restrict__ w2, u16* __restrict__ w2t) {
  __shared__ float tile[32][33];
  const int b = blockIdx.x;
  if (b < 1024) {
    int idx = b * 256 + threadIdx.x;                 // 0..262143
    int n = idx >> 9, k = idx & 511;
    float v = w[(n - k) & 511] * 0.04419417382415922f; // 1/sqrt(512)
    ct[idx] = f2bf(v);
    return;
  }
  const float* in;  u16* out;  int R, C, bx, by;
  if (b < 2048) {
    int l = b - 1024; in = w1; out = w1t; R = 512;  C = 2048;
    bx = (l & 63) * 32; by = (l >> 6) * 32;
  } else {
    int l = b - 2048; in = w2; out = w2t; R = 2048; C = 512;
    bx = (l & 15) * 32; by = (l >> 4) * 32;
  }
  int tx = threadIdx.x & 31, ty = threadIdx.x >> 5;
#pragma unroll
  for (int r = ty; r < 32; r += 8)
    tile[r][tx] = in[(size_t)(by + r) * C + bx + tx];
  __syncthreads();
#pragma unroll
  for (int r = ty; r < 32; r += 8)
    out[(size_t)(bx + r) * R + by + tx] = f2bf(tile[tx][r]);
}

// ---------------- LayerNorm [64,512] slab, fp32 in, single global read
__global__ __launch_bounds__(512, 2) void ln_f32(const float* __restrict__ x,
                                                 const float* __restrict__ g,
                                                 const float* __restrict__ beta,
                                                 u16* __restrict__ out) {
  const int tid = threadIdx.x;
  const size_t base = (size_t)blockIdx.x * 32768;
  float4 v[16];
  float s = 0.f, ss = 0.f;
#pragma unroll
  for (int j = 0; j < 16; ++j) {
    v[j] = *(const float4*)(x + base + tid * 4 + j * 2048);
    s  += v[j].x + v[j].y + v[j].z + v[j].w;
    ss += v[j].x * v[j].x + v[j].y * v[j].y + v[j].z * v[j].z + v[j].w * v[j].w;
  }
#pragma unroll
  for (int off = 32; off > 0; off >>= 1) {
    s += __shfl_down(s, off, 64);
    ss += __shfl_down(ss, off, 64);
  }
  __shared__ float red[16];
  int wave = tid >> 6, lane = tid & 63;
  if (lane == 0) { red[wave] = s; red[8 + wave] = ss; }
  __syncthreads();
  float S = 0.f, SS = 0.f;
#pragma unroll
  for (int wv = 0; wv < 8; ++wv) { S += red[wv]; SS += red[8 + wv]; }
  const float inv = 1.0f / 32768.0f;
  float mu = S * inv;
  float rs = rsqrtf(SS * inv - mu * mu + 1e-5f);
#pragma unroll
  for (int j = 0; j < 16; ++j) {
    const int i = tid * 4 + j * 2048;
    float4 gv = *(const float4*)(g + i);
    float4 bv = *(const float4*)(beta + i);
    uint2 o;
    o.x = (unsigned)f2bf((v[j].x - mu) * rs * gv.x + bv.x) |
          ((unsigned)f2bf((v[j].y - mu) * rs * gv.y + bv.y) << 16);
    o.y = (unsigned)f2bf((v[j].z - mu) * rs * gv.z + bv.z) |
          ((unsigned)f2bf((v[j].w - mu) * rs * gv.w + bv.w) << 16);
    *(uint2*)(out + base + i) = o;
  }
}

// ---------------- LayerNorm [64,512] slab, bf16 in, single global read
__global__ __launch_bounds__(512, 2) void ln_bf16(const u16* __restrict__ x,
                                                  const float* __restrict__ g,
                                                  const float* __restrict__ beta,
                                                  u16* __restrict__ out) {
  const int tid = threadIdx.x;
  const size_t base = (size_t)blockIdx.x * 32768;
  uint4 v[8];
  float s = 0.f, ss = 0.f;
#pragma unroll
  for (int j = 0; j < 8; ++j) {
    v[j] = *(const uint4*)(x + base + tid * 8 + j * 4096);
    const unsigned* a = &v[j].x;
#pragma unroll
    for (int t = 0; t < 4; ++t) {
      float lo = bf2f((u16)(a[t] & 0xffff)), hi = bf2f((u16)(a[t] >> 16));
      s += lo + hi; ss += lo * lo + hi * hi;
    }
  }
#pragma unroll
  for (int off = 32; off > 0; off >>= 1) {
    s += __shfl_down(s, off, 64);
    ss += __shfl_down(ss, off, 64);
  }
  __shared__ float red[16];
  int wave = tid >> 6, lane = tid & 63;
  if (lane == 0) { red[wave] = s; red[8 + wave] = ss; }
  __syncthreads();
  float S = 0.f, SS = 0.f;
#pragma unroll
  for (int wv = 0; wv < 8; ++wv) { S += red[wv]; SS += red[8 + wv]; }
  const float inv = 1.0f / 32768.0f;
  float mu = S * inv;
  float rs = rsqrtf(SS * inv - mu * mu + 1e-5f);
#pragma unroll
  for (int j = 0; j < 8; ++j) {
    const int i = tid * 8 + j * 4096;
    const unsigned* a = &v[j].x;
    uint4 o;
    unsigned* ov = &o.x;
#pragma unroll
    for (int t = 0; t < 4; ++t) {
      float lo = bf2f((u16)(a[t] & 0xffff)), hi = bf2f((u16)(a[t] >> 16));
      float glo = g[i + 2 * t], ghi = g[i + 2 * t + 1];
      float blo = beta[i + 2 * t], bhi = beta[i + 2 * t + 1];
      ov[t] = (unsigned)f2bf((lo - mu) * rs * glo + blo) |
              ((unsigned)f2bf((hi - mu) * rs * ghi + bhi) << 16);
    }
    *(uint4*)(out + base + i) = o;
  }
}

// ---------------- GEMM: C[M,N] = A[M,K](bf16) @ Bt[N,K](bf16)^T, BK=64
// Round-0 verified core (128x128 tile, 256 thr, 2-barrier K-loop, chunk
// swizzle -> 0 bank conflicts). Round-5 additions:
//  * bijective XCD swizzle + bm-major decomposition (1D grid, NT param)
//  * LDS-staged coalesced epilogue: C-tile goes through As (16KB, idle after
//    the K-loop) and is written as uint4/float4 full lines. Fixes the
//    2-4B scalar store write-amplification (WRITE_SIZE 210MB vs 134/67 ideal).
//    MODE 2 also reads resid as float4.
// MODE 0: plain, bf16 out   MODE 1: +bias, ReLU, bf16 out
// MODE 2: +bias, +resid(fp32), fp32 out
template <int MODE>
__global__ __launch_bounds__(256, 4) void gemm_bt(
    const u16* __restrict__ A, const u16* __restrict__ Bt,
    const float* __restrict__ bias, const float* __restrict__ resid,
    float* __restrict__ Cf, u16* __restrict__ Cb, int M, int N, int K,
    int NT) {
  __shared__ u16 As[128 * 64] __attribute__((aligned(16)));
  __shared__ u16 Bs[128 * 64] __attribute__((aligned(16)));
  const int tid = threadIdx.x;
  const int wave = tid >> 6, lane = tid & 63;
  const int quad = lane >> 4, l16 = lane & 15;
  const int wm = (wave >> 1) * 64, wn = (wave & 1) * 64;

  // bijective XCD swizzle (m204); bm-major: consecutive wgid on one XCD
  // share the A-panel (128 rows, L2-resident) and cycle bn
  const int nwg = gridDim.x;
  const int q8 = nwg >> 3, r8 = nwg & 7;
  const int xcd = blockIdx.x & 7, loc = blockIdx.x >> 3;
  const int wgid =
      (xcd < r8 ? xcd * (q8 + 1) : r8 * (q8 + 1) + (xcd - r8) * q8) + loc;
  const int m0 = (wgid / NT) * 128, n0 = (wgid % NT) * 128;
  (void)M;

  f32x4 acc[4][4];
#pragma unroll
  for (int i = 0; i < 4; ++i)
#pragma unroll
    for (int j = 0; j < 4; ++j) acc[i][j] = (f32x4){0.f, 0.f, 0.f, 0.f};

  const int rbase = tid >> 3;                     // 0..31
  const int slot  = tid & 7;                      // 16B slot in row
  const int gcol  = (slot ^ (rbase & 7)) * 8;     // swizzled source col (u16)
  const int lofs  = tid * 8;                      // u16 units = rbase*64+slot*8

  const u16* ag = A + (size_t)(m0 + rbase) * K + gcol;
  const u16* bg = Bt + (size_t)(n0 + rbase) * K + gcol;
  const int swr = (l16 & 7);                      // read-side row swizzle bits

  for (int k0 = 0; k0 < K; k0 += 64) {
    __syncthreads();
#pragma unroll
    for (int j = 0; j < 4; ++j) {
      async16(ag + (size_t)(32 * j) * K + k0, &As[lofs + j * 2048]);
      async16(bg + (size_t)(32 * j) * K + k0, &Bs[lofs + j * 2048]);
    }
    __syncthreads();
#pragma unroll
    for (int h = 0; h < 2; ++h) {
      const int sw = (((h << 2) + quad) ^ swr) * 8;
      bf16x8 af[4], bfr[4];
#pragma unroll
      for (int i = 0; i < 4; ++i)
        af[i] = *(const bf16x8*)&As[(wm + i * 16 + l16) * 64 + sw];
#pragma unroll
      for (int j = 0; j < 4; ++j)
        bfr[j] = *(const bf16x8*)&Bs[(wn + j * 16 + l16) * 64 + sw];
#pragma unroll
      for (int i = 0; i < 4; ++i)
#pragma unroll
        for (int j = 0; j < 4; ++j)
          acc[i][j] = __builtin_amdgcn_mfma_f32_16x16x32_bf16(af[i], bfr[j],
                                                              acc[i][j], 0, 0, 0);
    }
  }

  // ---- coalesced epilogue through As (16KB staging) ----
  __syncthreads();            // all K-loop ds_reads done; As reusable

  if (MODE != 2) {
    // bf16 out: 2 passes of 64 rows (64x128 u16 = 16KB in As)
#pragma unroll
    for (int h = 0; h < 2; ++h) {
      if ((wave >> 1) == h) {
#pragma unroll
        for (int j = 0; j < 4; ++j) {
          float bj = 0.f;
          if (MODE >= 1) bj = bias[n0 + wn + j * 16 + l16];
#pragma unroll
          for (int i = 0; i < 4; ++i)
#pragma unroll
            for (int r = 0; r < 4; ++r) {
              float v = acc[i][j][r] + bj;
              if (MODE == 1) v = fmaxf(v, 0.f);
              As[(i * 16 + quad * 4 + r) * 128 + wn + j * 16 + l16] = f2bf(v);
            }
        }
      }
      __syncthreads();
      const int row = tid >> 2;                   // 0..63, 4 thr/row
#pragma unroll
      for (int c = 0; c < 4; ++c) {
        const int ch = c * 4 + (tid & 3);         // 16B chunk, quad-contig
        uint4 vv = *(const uint4*)&As[row * 128 + ch * 8];
        *(uint4*)&Cb[(size_t)(m0 + h * 64 + row) * N + n0 + ch * 8] = vv;
      }
      __syncthreads();
    }
  } else {
    // fp32 out + resid: 4 passes of 32 rows (32x128 f32 = 16KB in As)
    float* SF = (float*)As;
#pragma unroll
    for (int p = 0; p < 4; ++p) {
      if ((wave >> 1) == (p >> 1)) {
        const int i0 = (p & 1) * 2;
#pragma unroll
        for (int j = 0; j < 4; ++j) {
          const float bj = bias[n0 + wn + j * 16 + l16];
#pragma unroll
          for (int i2 = 0; i2 < 2; ++i2)
#pragma unroll
            for (int r = 0; r < 4; ++r)
              SF[(i2 * 16 + quad * 4 + r) * 128 + wn + j * 16 + l16] =
                  acc[i0 + i2][j][r] + bj;
        }
      }
      __syncthreads();
      const int row = tid >> 3;                   // 0..31, 8 thr/row
#pragma unroll
      for (int c = 0; c < 4; ++c) {
        const int ch = c * 8 + (tid & 7);         // 16B chunk, 8-contig
        const size_t idx = (size_t)(m0 + p * 32 + row) * N + n0 + ch * 4;
        float4 sv = *(const float4*)&SF[row * 128 + ch * 4];
        float4 rv = *(const float4*)&resid[idx];
        sv.x += rv.x; sv.y += rv.y; sv.z += rv.z; sv.w += rv.w;
        *(float4*)&Cf[idx] = sv;
      }
      __syncthreads();
    }
  }
}

extern "C" void kernel_launch(void* const* d_in, const int* in_sizes, int n_in,
                              void* d_out, int out_size, void* d_ws,
                              size_t ws_size, hipStream_t stream) {
  const float* x    = (const float*)d_in[0];  // [512,64,512] fp32
  const float* w    = (const float*)d_in[1];  // [1,512]
  const float* ln1w = (const float*)d_in[2];  // [64,512]
  const float* ln1b = (const float*)d_in[3];
  const float* ln2w = (const float*)d_in[4];
  const float* ln2b = (const float*)d_in[5];
  const float* w1   = (const float*)d_in[6];  // [512,2048]
  const float* b1   = (const float*)d_in[7];  // [2048]
  const float* w2   = (const float*)d_in[8];  // [2048,512]
  const float* b2   = (const float*)d_in[9];  // [512]
  float* out = (float*)d_out;                 // [512,64,512] fp32

  char* ws = (char*)d_ws;
  // y overlaps h1+h2 (both dead before FFN1 writes y)
  u16*   y   = (u16*)(ws);                  // [32768,2048] bf16  134,217,728 B @ 0
  u16*   h1  = (u16*)(ws);                  // [32768,512]  bf16   33,554,432 B @ 0
  u16*   h2  = (u16*)(ws + 33554432);       // [32768,512]  bf16   33,554,432 B
  u16*   h3  = (u16*)(ws + 134217728);      // [32768,512]  bf16   33,554,432 B
  u16*   ct  = (u16*)(ws + 167772160);      // [512,512]    bf16      524,288 B
  u16*   w1t = (u16*)(ws + 168296448);      // [2048,512]   bf16    2,097,152 B
  u16*   w2t = (u16*)(ws + 170393600);      // [512,2048]   bf16    2,097,152 B
  // peak ws use: 172,490,752 B

  // fused setup: ct + w1t + w2t in one launch
  setup_all<<<3072, 256, 0, stream>>>(w, ct, w1, w1t, w2, w2t);

  // LN1: x(fp32) -> h1(bf16), single global read
  ln_f32<<<512, 512, 0, stream>>>(x, ln1w, ln1b, h1);
  // freq filter: h2(bf16) = h1 @ C  (M=32768,N=512,K=512) -> 1024 blocks
  gemm_bt<0><<<1024, 256, 0, stream>>>(h1, ct, nullptr, nullptr,
                                       nullptr, h2, 32768, 512, 512, 4);
  // LN2: h2(bf16) -> h3(bf16)
  ln_bf16<<<512, 512, 0, stream>>>(h2, ln2w, ln2b, h3);
  // FFN1: y(bf16) = relu(h3 @ w1 + b1)  (N=2048) -> 4096 blocks
  gemm_bt<1><<<4096, 256, 0, stream>>>(h3, w1t, b1, nullptr,
                                       nullptr, y, 32768, 2048, 512, 16);
  // FFN2 + residual: out(fp32) = y @ w2 + b2 + x  (K=2048) -> 1024 blocks
  gemm_bt<2><<<1024, 256, 0, stream>>>(y, w2t, b2, x,
                                       out, nullptr, 32768, 512, 2048, 4);
}